// Round 13
// baseline (112.867 us; speedup 1.0000x reference)
//
#include <hip/hip_runtime.h>
#include <math.h>

// B=16384, S=64, V=25, E=64, H=64, 4H=256, C=3
// gates^T[gunit][brow] = W_fused[gunit][k] @ x^T[k][brow] via mfma_f32_16x16x32_bf16.
// A = weights (VGPR-stationary), B = activations (msg from global, h from LDS).
// K = 3 chunks of 32: ch0 = msg k=0..24 (+k=25 bias row, 1.0 in B), ch1/2 = h bf16.
// Weights pre-scaled: i,f,o rows by -log2(e); g rows by +2*log2(e).
// Block = 4 waves (256 thr) = 16 batch rows; wave cg owns h-units [16cg,16cg+16).
//
// R13 changes vs R12 (92us):
//  * msg-chunk MFMA HOISTED out of the post-barrier critical path: accm[i] =
//    mfma(W0, msg(s+1), 0) computed between ds_write and barrier (dead time);
//    post-barrier step is ds_read -> 8 MFMAs seeded with accm -> act -> write.
//    Numerically identical (same accumulation order).
//  * s_setprio(1) around the post-barrier MFMA cluster (independent blocks at
//    different phases -> scheduler can favor the MFMA-entering wave, m191).

using bf16x8 = __attribute__((ext_vector_type(8))) short;
using f32x4  = __attribute__((ext_vector_type(4))) float;
using f32x2  = __attribute__((ext_vector_type(2))) float;

union U16B { uint4 u; bf16x8 v; };

#define KE  1.4426950408889634f
#define K2E 2.8853900817779268f

__device__ __forceinline__ unsigned short f2bf(float x) {
    unsigned int u = __float_as_uint(x);
    u += 0x7FFFu + ((u >> 16) & 1u);           // RNE
    return (unsigned short)(u >> 16);
}
__device__ __forceinline__ float bf2f(unsigned short h) {
    return __uint_as_float(((unsigned int)h) << 16);
}

// A-fragment layout for 16x16x32: lane holds A[row=lane&15][k=(lane>>4)*8+j], j=0..7.
// wfrag[((ch*16+gt)*64+lane)*8+j]: tile gt covers gunits [16gt,16gt+16).
// ch0: combT[gunit][k] (k<25), k==25 -> bias; ch1/2: Whh[gunit][k].
// All values pre-scaled by s(gate): gate=gunit>>6 (i,f,g,o); s = (gate==2)? +K2E : -KE.
__global__ void prep_kernel(const float* __restrict__ emb,
                            const float* __restrict__ Wih,
                            const float* __restrict__ Whh,
                            const float* __restrict__ bih,
                            const float* __restrict__ bhh,
                            unsigned short* __restrict__ wfrag) {
    const int b = blockIdx.x, tid = threadIdx.x;
    const int ch = b >> 4, gt = b & 15;
    const int lane = tid >> 3, j = tid & 7;
    const int kloc = (lane >> 4) * 8 + j;       // 0..31
    const int gunit = 16 * gt + (lane & 15);    // 0..255
    float v = 0.f;
    if (ch == 0) {
        if (kloc < 25) {
            const float* ep = emb + kloc * 64;
            const float* wp = Wih + gunit * 64;
            float s = 0.f;
            #pragma unroll
            for (int e = 0; e < 64; ++e) s = fmaf(ep[e], wp[e], s);
            v = s;
        } else if (kloc == 25) {
            v = bih[gunit] + bhh[gunit];        // bias row
        }
    } else {
        v = Whh[gunit * 64 + (ch - 1) * 32 + kloc];
    }
    const int gate = gunit >> 6;
    const float s = (gate == 2) ? K2E : -KE;
    wfrag[((ch * 16 + gt) * 64 + lane) * 8 + j] = f2bf(s * v);
}

#define CVTPK(D, A, B_)                                                      \
    asm("v_cvt_pk_bf16_f32 %0, %1, %2" : "=v"(D) : "v"(A), "v"(B_));

// LDS-only barrier: h exchange needs lgkmcnt drained, NOT vmcnt — msg
// prefetch loads stay in flight across the barrier.
#define BARRIER()                                                            \
    asm volatile("s_waitcnt lgkmcnt(0)\n\ts_barrier" ::: "memory");

// Load a msg slice as raw f32 (8 regs) from PTR; consumed steps later.
#define LOADMSG(DST, PTR)                                                    \
    {                                                                        \
        const float* p_ = (PTR) + kq;                                        \
        if (kq < 24) {                                                       \
            _Pragma("unroll") for (int j = 0; j < 8; ++j) DST[j] = p_[j];    \
        } else {                                                             \
            DST[0] = p_[0]; DST[1] = 1.0f;   /* bias row k=25 */             \
            _Pragma("unroll") for (int j = 2; j < 8; ++j) DST[j] = 0.f;      \
        }                                                                    \
    }

#define CONVMSG(MB, MF)                                                      \
    {                                                                        \
        CVTPK(MB.u.x, MF[0], MF[1]) CVTPK(MB.u.y, MF[2], MF[3])              \
        CVTPK(MB.u.z, MF[4], MF[5]) CVTPK(MB.u.w, MF[6], MF[7])              \
    }

// One LSTM step S. accm holds W0*msg(S) (computed last step, pre-barrier).
// MF holds msg(S+1) raw f32 (loaded 2-3 steps ago); refilled with msg(S+3).
#define STEP(S, CURB, NXTB, MF)                                              \
    {                                                                        \
        bf16x8 bh0, bh1;                                                     \
        {                                                                    \
            int o0_ = (l16 * 128 + 0 * 64 + lq * 16) ^ swz;                  \
            int o1_ = (l16 * 128 + 1 * 64 + lq * 16) ^ swz;                  \
            bh0 = *(const bf16x8*)((CURB) + o0_);                            \
            bh1 = *(const bf16x8*)((CURB) + o1_);                            \
        }                                                                    \
        __builtin_amdgcn_s_setprio(1);                                       \
        f32x4 acc[4];                                                        \
        _Pragma("unroll") for (int i = 0; i < 4; ++i)                        \
            acc[i] = __builtin_amdgcn_mfma_f32_16x16x32_bf16(                \
                w[1][i], bh0, accm[i], 0, 0, 0);                             \
        _Pragma("unroll") for (int i = 0; i < 4; ++i)                        \
            acc[i] = __builtin_amdgcn_mfma_f32_16x16x32_bf16(                \
                w[2][i], bh1, acc[i], 0, 0, 0);                              \
        __builtin_amdgcn_s_setprio(0);                                       \
        unsigned hw0_, hw1_;                                                 \
        _Pragma("unroll") for (int pp = 0; pp < 2; ++pp) {                   \
            f32x2 ai, af, ag, ao;                                            \
            ai[0] = acc[0][2*pp]; ai[1] = acc[0][2*pp+1];                    \
            af[0] = acc[1][2*pp]; af[1] = acc[1][2*pp+1];                    \
            ag[0] = acc[2][2*pp]; ag[1] = acc[2][2*pp+1];                    \
            ao[0] = acc[3][2*pp]; ao[1] = acc[3][2*pp+1];                    \
            f32x2 ti, tf_, tg, to_;                                          \
            ti[0]  = __builtin_amdgcn_exp2f(ai[0]);                          \
            ti[1]  = __builtin_amdgcn_exp2f(ai[1]);                          \
            tf_[0] = __builtin_amdgcn_exp2f(af[0]);                          \
            tf_[1] = __builtin_amdgcn_exp2f(af[1]);                          \
            to_[0] = __builtin_amdgcn_exp2f(ao[0]);                          \
            to_[1] = __builtin_amdgcn_exp2f(ao[1]);                          \
            tg[0]  = __builtin_amdgcn_exp2f(-fabsf(ag[0]));                  \
            tg[1]  = __builtin_amdgcn_exp2f(-fabsf(ag[1]));                  \
            f32x2 F_ = tf_ + 1.f;                                            \
            f32x2 P_ = (ti + 1.f) * (tg + 1.f);                              \
            f32x2 D_ = P_ * F_;                                              \
            f32x2 G_ = (1.f - tg) * F_;                                      \
            G_[0] = copysignf(G_[0], ag[0]);                                 \
            G_[1] = copysignf(G_[1], ag[1]);                                 \
            f32x2 num_ = c2[pp] * P_ + G_;                                   \
            f32x2 rD_;                                                       \
            rD_[0] = __builtin_amdgcn_rcpf(D_[0]);                           \
            rD_[1] = __builtin_amdgcn_rcpf(D_[1]);                           \
            f32x2 cn_ = num_ * rD_;                                          \
            c2[pp] = cn_;                                                    \
            f32x2 kc_ = cn_ * K2E;                                           \
            f32x2 tc_;                                                       \
            tc_[0] = __builtin_amdgcn_exp2f(-fabsf(kc_[0]));                 \
            tc_[1] = __builtin_amdgcn_exp2f(-fabsf(kc_[1]));                 \
            f32x2 D2_ = (to_ + 1.f) * (tc_ + 1.f);                           \
            f32x2 rD2_;                                                      \
            rD2_[0] = __builtin_amdgcn_rcpf(D2_[0]);                         \
            rD2_[1] = __builtin_amdgcn_rcpf(D2_[1]);                         \
            f32x2 ot_ = (1.f - tc_) * rD2_;                                  \
            float h0_ = copysignf(ot_[0], cn_[0]);                           \
            float h1_ = copysignf(ot_[1], cn_[1]);                           \
            if (pp == 0) { CVTPK(hw0_, h0_, h1_) }                           \
            else         { CVTPK(hw1_, h0_, h1_) }                           \
        }                                                                    \
        *(uint2*)((NXTB) + offw) = make_uint2(hw0_, hw1_);                   \
        /* pre-barrier slot: seed accm with W0*msg(S+1) (no LDS dep) */      \
        if ((S) < 63) {                                                      \
            U16B mc_;                                                        \
            CONVMSG(mc_, MF)                                                 \
            if ((S) < 61) { LOADMSG(MF, mp) }                                \
            mp += 25;                                                        \
            _Pragma("unroll") for (int i = 0; i < 4; ++i)                    \
                accm[i] = __builtin_amdgcn_mfma_f32_16x16x32_bf16(           \
                    w[0][i], mc_.v, z4, 0, 0, 0);                            \
        }                                                                    \
        BARRIER()                                                            \
    }

__global__ __launch_bounds__(256, 4) void lstm_mfma(
    const float* __restrict__ msgs,
    const unsigned short* __restrict__ wfrag,
    const float* __restrict__ fcw,
    const float* __restrict__ fcb,
    float* __restrict__ out)
{
    // double-buffered h: buf = h[16 brows][64 units] bf16 = 2KB, x2
    __shared__ __align__(16) char lds[4096];

    const int tid  = threadIdx.x;
    const int lane = tid & 63;
    const int cg   = __builtin_amdgcn_readfirstlane(tid >> 6); // 0..3 (SGPR)
    const int l16  = lane & 15;                 // batch row within tile
    const int lq   = lane >> 4;                 // k-quad / unit-quad
    const int row0 = blockIdx.x * 16;
    const int kq   = lq * 8;                    // k base within chunk

    // weight A-fragments in VGPRs: gate i -> tile 4i+cg, 3 chunks (48 regs)
    bf16x8 w[3][4];
    #pragma unroll
    for (int ch = 0; ch < 3; ++ch)
        #pragma unroll
        for (int i = 0; i < 4; ++i)
            w[ch][i] = *(const bf16x8*)(wfrag + ((ch * 16 + 4 * i + cg) * 64 + lane) * 8);

    // zero h buffer 0 (2KB)
    for (int idx = tid; idx < 512; idx += 256) ((unsigned int*)lds)[idx] = 0u;

    // persistent zero C-operand for the msg-chunk MFMA
    const f32x4 z4 = (f32x4){0.f, 0.f, 0.f, 0.f};

    f32x2 c2[2];
    c2[0] = (f32x2){0.f, 0.f};
    c2[1] = (f32x2){0.f, 0.f};

    const float* mrow = msgs + (long)(row0 + l16) * 1600;
    const int swz  = (l16 & 7) << 4;
    // this thread writes h[brow=l16][units 16cg+4lq .. +3] -> 8B
    const int offw = (l16 * 128 + cg * 32 + lq * 8) ^ swz;

    // prologue: msg(0) -> accm; prefetch msg(1), msg(2); mp walks from msg(3)
    float mf0[8], mfA[8], mfB[8];
    LOADMSG(mf0, mrow)
    LOADMSG(mfA, mrow + 25)
    LOADMSG(mfB, mrow + 50)
    const float* mp = mrow + 75;

    f32x4 accm[4];
    {
        U16B mc0;
        CONVMSG(mc0, mf0)
        #pragma unroll
        for (int i = 0; i < 4; ++i)
            accm[i] = __builtin_amdgcn_mfma_f32_16x16x32_bf16(
                w[0][i], mc0.v, z4, 0, 0, 0);
    }
    __syncthreads();   // one-time full barrier (zeroed LDS visible)

    char* b0 = (char*)lds;
    char* b1 = b0 + 2048;
    for (int s2 = 0; s2 < 64; s2 += 2) {
        STEP(s2,     b0, b1, mfA)
        STEP(s2 + 1, b1, b0, mfB)
    }

    // final h in b0 as h[brow][unit]. FC epilogue: thread -> (row, class)
    if (tid < 64) {
        const int r = tid >> 2, cls = tid & 3;
        if (cls < 3) {
            float a = fcb[cls];
            const int sw = (r & 7) << 4;
            #pragma unroll
            for (int u = 0; u < 64; ++u) {
                int off = (r * 128 + u * 2) ^ sw;
                float hv = bf2f(*(const unsigned short*)(b0 + off));
                a = fmaf(hv, fcw[cls * 64 + u], a);
            }
            out[(row0 + r) * 3 + cls] = a;
        }
    }
}

extern "C" void kernel_launch(void* const* d_in, const int* in_sizes, int n_in,
                              void* d_out, int out_size, void* d_ws, size_t ws_size,
                              hipStream_t stream) {
    const float* msgs = (const float*)d_in[0];
    const float* emb  = (const float*)d_in[1];
    const float* Wih  = (const float*)d_in[2];
    const float* Whh  = (const float*)d_in[3];
    const float* bih  = (const float*)d_in[4];
    const float* bhh  = (const float*)d_in[5];
    const float* fcw  = (const float*)d_in[6];
    const float* fcb  = (const float*)d_in[7];
    float* out = (float*)d_out;

    // ws: wfrag bf16[3*16*64*8] = 49152 B
    unsigned short* wfrag = (unsigned short*)d_ws;

    prep_kernel<<<48, 512, 0, stream>>>(emb, Wih, Whh, bih, bhh, wfrag);
    lstm_mfma<<<16384 / 16, 256, 0, stream>>>(msgs, wfrag, fcw, fcb, out);
}

// Round 14
// 101.778 us; speedup vs baseline: 1.1089x; 1.1089x over previous
//
#include <hip/hip_runtime.h>
#include <math.h>

// B=16384, S=64, V=25, E=64, H=64, 4H=256, C=3
// gates^T[gunit][brow] = W_fused[gunit][k] @ x^T[k][brow] via mfma_f32_16x16x32_bf16.
// A = weights (VGPR-stationary), B = activations (msg from global, h from LDS).
// K = 3 chunks of 32: ch0 = msg k=0..24 (+k=25 bias row), ch1/2 = h bf16.
// Weights pre-scaled: i,f,o rows by -log2(e); g rows by +2*log2(e).
//
// R14 vs R12 (92us): TWO independent 16-row tiles per wave (same unit slice ->
// same weight frags). Between barriers each wave has two independent step
// bodies (tile A act || tile B MFMAs) -> in-wave ILP fills the chain stalls
// that 4-waves/SIMD couldn't. Block = 4 waves / 32 rows; grid 512.
// R13's setprio + accm hoist reverted (regressed).

using bf16x8 = __attribute__((ext_vector_type(8))) short;
using f32x4  = __attribute__((ext_vector_type(4))) float;
using f32x2  = __attribute__((ext_vector_type(2))) float;

union U16B { uint4 u; bf16x8 v; };

#define KE  1.4426950408889634f
#define K2E 2.8853900817779268f

__device__ __forceinline__ unsigned short f2bf(float x) {
    unsigned int u = __float_as_uint(x);
    u += 0x7FFFu + ((u >> 16) & 1u);           // RNE
    return (unsigned short)(u >> 16);
}
__device__ __forceinline__ float bf2f(unsigned short h) {
    return __uint_as_float(((unsigned int)h) << 16);
}

// A-fragment layout: lane holds A[row=lane&15][k=(lane>>4)*8+j], j=0..7.
// wfrag[((ch*16+gt)*64+lane)*8+j]: tile gt covers gunits [16gt,16gt+16).
// ch0: combT[gunit][k] (k<25), k==25 -> bias; ch1/2: Whh[gunit][k].
// Pre-scaled by s(gate): gate=gunit>>6; s = (gate==2)? +K2E : -KE.
__global__ void prep_kernel(const float* __restrict__ emb,
                            const float* __restrict__ Wih,
                            const float* __restrict__ Whh,
                            const float* __restrict__ bih,
                            const float* __restrict__ bhh,
                            unsigned short* __restrict__ wfrag) {
    const int b = blockIdx.x, tid = threadIdx.x;
    const int ch = b >> 4, gt = b & 15;
    const int lane = tid >> 3, j = tid & 7;
    const int kloc = (lane >> 4) * 8 + j;       // 0..31
    const int gunit = 16 * gt + (lane & 15);    // 0..255
    float v = 0.f;
    if (ch == 0) {
        if (kloc < 25) {
            const float* ep = emb + kloc * 64;
            const float* wp = Wih + gunit * 64;
            float s = 0.f;
            #pragma unroll
            for (int e = 0; e < 64; ++e) s = fmaf(ep[e], wp[e], s);
            v = s;
        } else if (kloc == 25) {
            v = bih[gunit] + bhh[gunit];        // bias row
        }
    } else {
        v = Whh[gunit * 64 + (ch - 1) * 32 + kloc];
    }
    const int gate = gunit >> 6;
    const float s = (gate == 2) ? K2E : -KE;
    wfrag[((ch * 16 + gt) * 64 + lane) * 8 + j] = f2bf(s * v);
}

#define CVTPK(D, A, B_)                                                      \
    asm("v_cvt_pk_bf16_f32 %0, %1, %2" : "=v"(D) : "v"(A), "v"(B_));

// LDS-only barrier: msg prefetch loads stay in flight (no vmcnt drain).
#define BARRIER()                                                            \
    asm volatile("s_waitcnt lgkmcnt(0)\n\ts_barrier" ::: "memory");

#define LOADMSG(DST, PTR)                                                    \
    {                                                                        \
        const float* p_ = (PTR) + kq;                                        \
        if (kq < 24) {                                                       \
            _Pragma("unroll") for (int j = 0; j < 8; ++j) DST[j] = p_[j];    \
        } else {                                                             \
            DST[0] = p_[0]; DST[1] = 1.0f;   /* bias row k=25 */             \
            _Pragma("unroll") for (int j = 2; j < 8; ++j) DST[j] = 0.f;      \
        }                                                                    \
    }

#define CONVMSG(MB, MF)                                                      \
    {                                                                        \
        CVTPK(MB.u.x, MF[0], MF[1]) CVTPK(MB.u.y, MF[2], MF[3])              \
        CVTPK(MB.u.z, MF[4], MF[5]) CVTPK(MB.u.w, MF[6], MF[7])              \
    }

// One LSTM step body for one row-tile (no barrier inside; caller barriers).
// MF: f32[8] msg(S); refilled with msg(S+2). C2: this tile's c state.
// MP: this tile's msg prefetch pointer. OFFW: h write offset in tile buffer.
#define STEP(S, CURB, NXTB, MF, C2, OFFW, MP)                                \
    {                                                                        \
        bf16x8 bh0, bh1;                                                     \
        bh0 = *(const bf16x8*)((CURB) + ro0);                                \
        bh1 = *(const bf16x8*)((CURB) + ro1);                                \
        U16B mc_;                                                            \
        CONVMSG(mc_, MF)                                                     \
        if ((S) < 62) { LOADMSG(MF, MP) }                                    \
        MP += 25;                                                            \
        f32x4 acc[4];                                                        \
        _Pragma("unroll") for (int i = 0; i < 4; ++i)                        \
            acc[i] = __builtin_amdgcn_mfma_f32_16x16x32_bf16(                \
                w[0][i], mc_.v, z4, 0, 0, 0);                                \
        _Pragma("unroll") for (int i = 0; i < 4; ++i)                        \
            acc[i] = __builtin_amdgcn_mfma_f32_16x16x32_bf16(                \
                w[1][i], bh0, acc[i], 0, 0, 0);                              \
        _Pragma("unroll") for (int i = 0; i < 4; ++i)                        \
            acc[i] = __builtin_amdgcn_mfma_f32_16x16x32_bf16(                \
                w[2][i], bh1, acc[i], 0, 0, 0);                              \
        unsigned hw0_, hw1_;                                                 \
        _Pragma("unroll") for (int pp = 0; pp < 2; ++pp) {                   \
            f32x2 ai, af, ag, ao;                                            \
            ai[0] = acc[0][2*pp]; ai[1] = acc[0][2*pp+1];                    \
            af[0] = acc[1][2*pp]; af[1] = acc[1][2*pp+1];                    \
            ag[0] = acc[2][2*pp]; ag[1] = acc[2][2*pp+1];                    \
            ao[0] = acc[3][2*pp]; ao[1] = acc[3][2*pp+1];                    \
            f32x2 ti, tf_, tg, to_;                                          \
            ti[0]  = __builtin_amdgcn_exp2f(ai[0]);                          \
            ti[1]  = __builtin_amdgcn_exp2f(ai[1]);                          \
            tf_[0] = __builtin_amdgcn_exp2f(af[0]);                          \
            tf_[1] = __builtin_amdgcn_exp2f(af[1]);                          \
            to_[0] = __builtin_amdgcn_exp2f(ao[0]);                          \
            to_[1] = __builtin_amdgcn_exp2f(ao[1]);                          \
            tg[0]  = __builtin_amdgcn_exp2f(-fabsf(ag[0]));                  \
            tg[1]  = __builtin_amdgcn_exp2f(-fabsf(ag[1]));                  \
            f32x2 F_ = tf_ + 1.f;                                            \
            f32x2 P_ = (ti + 1.f) * (tg + 1.f);                              \
            f32x2 D_ = P_ * F_;                                              \
            f32x2 G_ = (1.f - tg) * F_;                                      \
            G_[0] = copysignf(G_[0], ag[0]);                                 \
            G_[1] = copysignf(G_[1], ag[1]);                                 \
            f32x2 num_ = C2[pp] * P_ + G_;                                   \
            f32x2 rD_;                                                       \
            rD_[0] = __builtin_amdgcn_rcpf(D_[0]);                           \
            rD_[1] = __builtin_amdgcn_rcpf(D_[1]);                           \
            f32x2 cn_ = num_ * rD_;                                          \
            C2[pp] = cn_;                                                    \
            f32x2 kc_ = cn_ * K2E;                                           \
            f32x2 tc_;                                                       \
            tc_[0] = __builtin_amdgcn_exp2f(-fabsf(kc_[0]));                 \
            tc_[1] = __builtin_amdgcn_exp2f(-fabsf(kc_[1]));                 \
            f32x2 D2_ = (to_ + 1.f) * (tc_ + 1.f);                           \
            f32x2 rD2_;                                                      \
            rD2_[0] = __builtin_amdgcn_rcpf(D2_[0]);                         \
            rD2_[1] = __builtin_amdgcn_rcpf(D2_[1]);                         \
            f32x2 ot_ = (1.f - tc_) * rD2_;                                  \
            float h0_ = copysignf(ot_[0], cn_[0]);                           \
            float h1_ = copysignf(ot_[1], cn_[1]);                           \
            if (pp == 0) { CVTPK(hw0_, h0_, h1_) }                           \
            else         { CVTPK(hw1_, h0_, h1_) }                           \
        }                                                                    \
        *(uint2*)((NXTB) + (OFFW)) = make_uint2(hw0_, hw1_);                 \
    }

__global__ __launch_bounds__(256, 2) void lstm_mfma(
    const float* __restrict__ msgs,
    const unsigned short* __restrict__ wfrag,
    const float* __restrict__ fcw,
    const float* __restrict__ fcb,
    float* __restrict__ out)
{
    // LDS: tile0 h dbuf @0/@2048, tile1 h dbuf @4096/@6144 (2KB each)
    __shared__ __align__(16) char lds[8192];

    const int tid  = threadIdx.x;
    const int lane = tid & 63;
    const int cg   = __builtin_amdgcn_readfirstlane(tid >> 6); // 0..3 (SGPR)
    const int l16  = lane & 15;                 // batch row within tile
    const int lq   = lane >> 4;                 // k-quad / unit-quad
    const int row0 = blockIdx.x * 32;
    const int kq   = lq * 8;                    // k base within chunk

    // weight A-fragments: gate i -> tile 4i+cg, 3 chunks (48 regs, shared by both row-tiles)
    bf16x8 w[3][4];
    #pragma unroll
    for (int ch = 0; ch < 3; ++ch)
        #pragma unroll
        for (int i = 0; i < 4; ++i)
            w[ch][i] = *(const bf16x8*)(wfrag + ((ch * 16 + 4 * i + cg) * 64 + lane) * 8);

    // zero both tiles' h buffer 0
    for (int idx = tid; idx < 512; idx += 256) {
        ((unsigned int*)lds)[idx] = 0u;                  // tile0 buf0
        ((unsigned int*)(lds + 4096))[idx] = 0u;         // tile1 buf0
    }

    const f32x4 z4 = (f32x4){0.f, 0.f, 0.f, 0.f};

    f32x2 c2a[2], c2b[2];
    c2a[0] = (f32x2){0.f, 0.f}; c2a[1] = (f32x2){0.f, 0.f};
    c2b[0] = (f32x2){0.f, 0.f}; c2b[1] = (f32x2){0.f, 0.f};

    const int swz  = (l16 & 7) << 4;
    const int ro0  = (l16 * 128 + lq * 16) ^ swz;        // h read offs (loop-invariant)
    const int ro1  = (l16 * 128 + 64 + lq * 16) ^ swz;
    const int offw = (l16 * 128 + cg * 32 + lq * 8) ^ swz;

    const float* mrow0 = msgs + (long)(row0 + l16) * 1600;
    const float* mrow1 = msgs + (long)(row0 + 16 + l16) * 1600;

    // per-tile msg prefetch (depth 2)
    float mA0[8], mB0[8], mA1[8], mB1[8];
    LOADMSG(mA0, mrow0)
    LOADMSG(mB0, mrow0 + 25)
    LOADMSG(mA1, mrow1)
    LOADMSG(mB1, mrow1 + 25)
    const float* mp0 = mrow0 + 50;
    const float* mp1 = mrow1 + 50;

    __syncthreads();   // one-time full barrier (zeroed LDS visible)

    char* t0b0 = (char*)lds;
    char* t0b1 = t0b0 + 2048;
    char* t1b0 = t0b0 + 4096;
    char* t1b1 = t0b0 + 6144;

    for (int s2 = 0; s2 < 64; s2 += 2) {
        STEP(s2, t0b0, t0b1, mA0, c2a, offw, mp0)
        STEP(s2, t1b0, t1b1, mA1, c2b, offw, mp1)
        BARRIER()
        STEP(s2 + 1, t0b1, t0b0, mB0, c2a, offw, mp0)
        STEP(s2 + 1, t1b1, t1b0, mB1, c2b, offw, mp1)
        BARRIER()
    }

    // final h in each tile's buf0. FC epilogue: thread -> (row 0..31, class)
    if (tid < 128) {
        const int r = tid >> 2, cls = tid & 3;
        if (cls < 3) {
            const char* hb = (r < 16) ? t0b0 : t1b0;
            const int rr = r & 15;
            float a = fcb[cls];
            const int sw = (rr & 7) << 4;
            #pragma unroll
            for (int u = 0; u < 64; ++u) {
                int off = (rr * 128 + u * 2) ^ sw;
                float hv = bf2f(*(const unsigned short*)(hb + off));
                a = fmaf(hv, fcw[cls * 64 + u], a);
            }
            out[(row0 + r) * 3 + cls] = a;
        }
    }
}

extern "C" void kernel_launch(void* const* d_in, const int* in_sizes, int n_in,
                              void* d_out, int out_size, void* d_ws, size_t ws_size,
                              hipStream_t stream) {
    const float* msgs = (const float*)d_in[0];
    const float* emb  = (const float*)d_in[1];
    const float* Wih  = (const float*)d_in[2];
    const float* Whh  = (const float*)d_in[3];
    const float* bih  = (const float*)d_in[4];
    const float* bhh  = (const float*)d_in[5];
    const float* fcw  = (const float*)d_in[6];
    const float* fcb  = (const float*)d_in[7];
    float* out = (float*)d_out;

    // ws: wfrag bf16[3*16*64*8] = 49152 B
    unsigned short* wfrag = (unsigned short*)d_ws;

    prep_kernel<<<48, 512, 0, stream>>>(emb, Wih, Whh, bih, bhh, wfrag);
    lstm_mfma<<<16384 / 32, 256, 0, stream>>>(msgs, wfrag, fcw, fcb, out);
}

// Round 18
// 92.650 us; speedup vs baseline: 1.2182x; 1.0985x over previous
//
#include <hip/hip_runtime.h>
#include <math.h>

// B=16384, S=64, V=25, E=64, H=64, 4H=256, C=3
// gates^T[gunit][brow] = W_fused[gunit][k] @ x^T[k][brow] via mfma_f32_16x16x32_bf16.
// A = weights (VGPR-stationary), B = activations (msg from global, h from LDS).
// K = 3 chunks of 32: ch0 = msg k=0..24 (+k=25 bias row, 1.0 in B), ch1/2 = h bf16.
// Weights pre-scaled: i,f,o rows by -log2(e); g rows by +2*log2(e).
// Block = 4 waves (256 thr) = 16 batch rows; wave cg owns h-units [16cg,16cg+16).
//
// R18 = R12 verbatim (session best, 92.3us). Gate-split lineage (R15-R17)
// abandoned after 3 NaN rounds; R13 (hoist+setprio) and R14 (dual-tile)
// regressed. This re-establishes the known-good baseline.
//  * LDS-only step barrier (lgkmcnt drain, msg prefetch stays in flight)
//  * msg prefetch depth 2 (raw f32, cvt_pk at consumption)
//  * persistent zero C-operand; single-rcp cell; packed f32 activation math

using bf16x8 = __attribute__((ext_vector_type(8))) short;
using f32x4  = __attribute__((ext_vector_type(4))) float;
using f32x2  = __attribute__((ext_vector_type(2))) float;

union U16B { uint4 u; bf16x8 v; };

#define KE  1.4426950408889634f
#define K2E 2.8853900817779268f

__device__ __forceinline__ unsigned short f2bf(float x) {
    unsigned int u = __float_as_uint(x);
    u += 0x7FFFu + ((u >> 16) & 1u);           // RNE
    return (unsigned short)(u >> 16);
}
__device__ __forceinline__ float bf2f(unsigned short h) {
    return __uint_as_float(((unsigned int)h) << 16);
}

// A-fragment layout for 16x16x32: lane holds A[row=lane&15][k=(lane>>4)*8+j], j=0..7.
// wfrag[((ch*16+gt)*64+lane)*8+j]: tile gt covers gunits [16gt,16gt+16).
// ch0: combT[gunit][k] (k<25), k==25 -> bias; ch1/2: Whh[gunit][k].
// All values pre-scaled by s(gate): gate=gunit>>6 (i,f,g,o); s = (gate==2)? +K2E : -KE.
__global__ void prep_kernel(const float* __restrict__ emb,
                            const float* __restrict__ Wih,
                            const float* __restrict__ Whh,
                            const float* __restrict__ bih,
                            const float* __restrict__ bhh,
                            unsigned short* __restrict__ wfrag) {
    const int b = blockIdx.x, tid = threadIdx.x;
    const int ch = b >> 4, gt = b & 15;
    const int lane = tid >> 3, j = tid & 7;
    const int kloc = (lane >> 4) * 8 + j;       // 0..31
    const int gunit = 16 * gt + (lane & 15);    // 0..255
    float v = 0.f;
    if (ch == 0) {
        if (kloc < 25) {
            const float* ep = emb + kloc * 64;
            const float* wp = Wih + gunit * 64;
            float s = 0.f;
            #pragma unroll
            for (int e = 0; e < 64; ++e) s = fmaf(ep[e], wp[e], s);
            v = s;
        } else if (kloc == 25) {
            v = bih[gunit] + bhh[gunit];        // bias row
        }
    } else {
        v = Whh[gunit * 64 + (ch - 1) * 32 + kloc];
    }
    const int gate = gunit >> 6;
    const float s = (gate == 2) ? K2E : -KE;
    wfrag[((ch * 16 + gt) * 64 + lane) * 8 + j] = f2bf(s * v);
}

#define CVTPK(D, A, B_)                                                      \
    asm("v_cvt_pk_bf16_f32 %0, %1, %2" : "=v"(D) : "v"(A), "v"(B_));

// LDS-only barrier: h exchange needs lgkmcnt drained, NOT vmcnt — msg
// prefetch loads stay in flight across the barrier.
#define BARRIER()                                                            \
    asm volatile("s_waitcnt lgkmcnt(0)\n\ts_barrier" ::: "memory");

// Load next msg slice as raw f32 (8 regs) from PTR; consumed 2 steps later.
#define LOADMSG(DST, PTR)                                                    \
    {                                                                        \
        const float* p_ = (PTR) + kq;                                        \
        if (kq < 24) {                                                       \
            _Pragma("unroll") for (int j = 0; j < 8; ++j) DST[j] = p_[j];    \
        } else {                                                             \
            DST[0] = p_[0]; DST[1] = 1.0f;   /* bias row k=25 */             \
            _Pragma("unroll") for (int j = 2; j < 8; ++j) DST[j] = 0.f;      \
        }                                                                    \
    }

#define CONVMSG(MB, MF)                                                      \
    {                                                                        \
        CVTPK(MB.u.x, MF[0], MF[1]) CVTPK(MB.u.y, MF[2], MF[3])              \
        CVTPK(MB.u.z, MF[4], MF[5]) CVTPK(MB.u.w, MF[6], MF[7])              \
    }

// One LSTM step. MF holds step S's msg (f32), refilled with step S+2's.
#define STEP(S, CURB, NXTB, MF)                                              \
    {                                                                        \
        bf16x8 bh0, bh1;                                                     \
        {                                                                    \
            int o0_ = (l16 * 128 + 0 * 64 + lq * 16) ^ swz;                  \
            int o1_ = (l16 * 128 + 1 * 64 + lq * 16) ^ swz;                  \
            bh0 = *(const bf16x8*)((CURB) + o0_);                            \
            bh1 = *(const bf16x8*)((CURB) + o1_);                            \
        }                                                                    \
        U16B mc_;                                                            \
        CONVMSG(mc_, MF)                                                     \
        if ((S) < 62) { LOADMSG(MF, mp) }                                    \
        mp += 25;                                                            \
        f32x4 acc[4];                                                        \
        _Pragma("unroll") for (int i = 0; i < 4; ++i)                        \
            acc[i] = __builtin_amdgcn_mfma_f32_16x16x32_bf16(                \
                w[0][i], mc_.v, z4, 0, 0, 0);                                \
        _Pragma("unroll") for (int i = 0; i < 4; ++i)                        \
            acc[i] = __builtin_amdgcn_mfma_f32_16x16x32_bf16(                \
                w[1][i], bh0, acc[i], 0, 0, 0);                              \
        _Pragma("unroll") for (int i = 0; i < 4; ++i)                        \
            acc[i] = __builtin_amdgcn_mfma_f32_16x16x32_bf16(                \
                w[2][i], bh1, acc[i], 0, 0, 0);                              \
        unsigned hw0_, hw1_;                                                 \
        _Pragma("unroll") for (int pp = 0; pp < 2; ++pp) {                   \
            f32x2 ai, af, ag, ao;                                            \
            ai[0] = acc[0][2*pp]; ai[1] = acc[0][2*pp+1];                    \
            af[0] = acc[1][2*pp]; af[1] = acc[1][2*pp+1];                    \
            ag[0] = acc[2][2*pp]; ag[1] = acc[2][2*pp+1];                    \
            ao[0] = acc[3][2*pp]; ao[1] = acc[3][2*pp+1];                    \
            f32x2 ti, tf_, tg, to_;                                          \
            ti[0]  = __builtin_amdgcn_exp2f(ai[0]);                          \
            ti[1]  = __builtin_amdgcn_exp2f(ai[1]);                          \
            tf_[0] = __builtin_amdgcn_exp2f(af[0]);                          \
            tf_[1] = __builtin_amdgcn_exp2f(af[1]);                          \
            to_[0] = __builtin_amdgcn_exp2f(ao[0]);                          \
            to_[1] = __builtin_amdgcn_exp2f(ao[1]);                          \
            tg[0]  = __builtin_amdgcn_exp2f(-fabsf(ag[0]));                  \
            tg[1]  = __builtin_amdgcn_exp2f(-fabsf(ag[1]));                  \
            f32x2 F_ = tf_ + 1.f;                                            \
            f32x2 P_ = (ti + 1.f) * (tg + 1.f);                              \
            f32x2 D_ = P_ * F_;                                              \
            f32x2 G_ = (1.f - tg) * F_;                                      \
            G_[0] = copysignf(G_[0], ag[0]);                                 \
            G_[1] = copysignf(G_[1], ag[1]);                                 \
            f32x2 num_ = c2[pp] * P_ + G_;                                   \
            f32x2 rD_;                                                       \
            rD_[0] = __builtin_amdgcn_rcpf(D_[0]);                           \
            rD_[1] = __builtin_amdgcn_rcpf(D_[1]);                           \
            f32x2 cn_ = num_ * rD_;                                          \
            c2[pp] = cn_;                                                    \
            f32x2 kc_ = cn_ * K2E;                                           \
            f32x2 tc_;                                                       \
            tc_[0] = __builtin_amdgcn_exp2f(-fabsf(kc_[0]));                 \
            tc_[1] = __builtin_amdgcn_exp2f(-fabsf(kc_[1]));                 \
            f32x2 D2_ = (to_ + 1.f) * (tc_ + 1.f);                           \
            f32x2 rD2_;                                                      \
            rD2_[0] = __builtin_amdgcn_rcpf(D2_[0]);                         \
            rD2_[1] = __builtin_amdgcn_rcpf(D2_[1]);                         \
            f32x2 ot_ = (1.f - tc_) * rD2_;                                  \
            float h0_ = copysignf(ot_[0], cn_[0]);                           \
            float h1_ = copysignf(ot_[1], cn_[1]);                           \
            if (pp == 0) { CVTPK(hw0_, h0_, h1_) }                           \
            else         { CVTPK(hw1_, h0_, h1_) }                           \
        }                                                                    \
        *(uint2*)((NXTB) + offw) = make_uint2(hw0_, hw1_);                   \
        BARRIER()                                                            \
    }

__global__ __launch_bounds__(256, 4) void lstm_mfma(
    const float* __restrict__ msgs,
    const unsigned short* __restrict__ wfrag,
    const float* __restrict__ fcw,
    const float* __restrict__ fcb,
    float* __restrict__ out)
{
    // double-buffered h: buf = h[16 brows][64 units] bf16 = 2KB, x2
    __shared__ __align__(16) char lds[4096];

    const int tid  = threadIdx.x;
    const int lane = tid & 63;
    const int cg   = __builtin_amdgcn_readfirstlane(tid >> 6); // 0..3 (SGPR)
    const int l16  = lane & 15;                 // batch row within tile
    const int lq   = lane >> 4;                 // k-quad / unit-quad
    const int row0 = blockIdx.x * 16;
    const int kq   = lq * 8;                    // k base within chunk

    // weight A-fragments in VGPRs: gate i -> tile 4i+cg, 3 chunks (48 regs)
    bf16x8 w[3][4];
    #pragma unroll
    for (int ch = 0; ch < 3; ++ch)
        #pragma unroll
        for (int i = 0; i < 4; ++i)
            w[ch][i] = *(const bf16x8*)(wfrag + ((ch * 16 + 4 * i + cg) * 64 + lane) * 8);

    // zero h buffer 0 (2KB)
    for (int idx = tid; idx < 512; idx += 256) ((unsigned int*)lds)[idx] = 0u;

    // persistent zero C-operand for the first MFMA of each chain
    const f32x4 z4 = (f32x4){0.f, 0.f, 0.f, 0.f};

    f32x2 c2[2];
    c2[0] = (f32x2){0.f, 0.f};
    c2[1] = (f32x2){0.f, 0.f};

    const float* mrow = msgs + (long)(row0 + l16) * 1600;
    const float* mp   = mrow + 50;              // next msg slice to prefetch (s=2)
    const int swz  = (l16 & 7) << 4;
    // this thread writes h[brow=l16][units 16cg+4lq .. +3] -> 8B
    const int offw = (l16 * 128 + cg * 32 + lq * 8) ^ swz;

    float mfA[8], mfB[8];
    LOADMSG(mfA, mrow)
    LOADMSG(mfB, mrow + 25)
    __syncthreads();   // one-time full barrier (zeroed LDS visible)

    char* b0 = (char*)lds;
    char* b1 = b0 + 2048;
    for (int s2 = 0; s2 < 64; s2 += 2) {
        STEP(s2,     b0, b1, mfA)
        STEP(s2 + 1, b1, b0, mfB)
    }

    // final h in b0 as h[brow][unit]. FC epilogue: thread -> (row, class)
    if (tid < 64) {
        const int r = tid >> 2, cls = tid & 3;
        if (cls < 3) {
            float a = fcb[cls];
            const int sw = (r & 7) << 4;
            #pragma unroll
            for (int u = 0; u < 64; ++u) {
                int off = (r * 128 + u * 2) ^ sw;
                float hv = bf2f(*(const unsigned short*)(b0 + off));
                a = fmaf(hv, fcw[cls * 64 + u], a);
            }
            out[(row0 + r) * 3 + cls] = a;
        }
    }
}

extern "C" void kernel_launch(void* const* d_in, const int* in_sizes, int n_in,
                              void* d_out, int out_size, void* d_ws, size_t ws_size,
                              hipStream_t stream) {
    const float* msgs = (const float*)d_in[0];
    const float* emb  = (const float*)d_in[1];
    const float* Wih  = (const float*)d_in[2];
    const float* Whh  = (const float*)d_in[3];
    const float* bih  = (const float*)d_in[4];
    const float* bhh  = (const float*)d_in[5];
    const float* fcw  = (const float*)d_in[6];
    const float* fcb  = (const float*)d_in[7];
    float* out = (float*)d_out;

    // ws: wfrag bf16[3*16*64*8] = 49152 B
    unsigned short* wfrag = (unsigned short*)d_ws;

    prep_kernel<<<48, 512, 0, stream>>>(emb, Wih, Whh, bih, bhh, wfrag);
    lstm_mfma<<<16384 / 16, 256, 0, stream>>>(msgs, wfrag, fcw, fcb, out);
}

// Round 19
// 90.251 us; speedup vs baseline: 1.2506x; 1.0266x over previous
//
#include <hip/hip_runtime.h>
#include <math.h>

// B=16384, S=64, V=25, E=64, H=64, 4H=256, C=3
// gates^T[gunit][brow] = W_fused[gunit][k] @ x^T[k][brow] via mfma_f32_16x16x32_bf16.
// A = weights (VGPR-stationary), B = activations (msg from global, h from LDS).
// K = 3 chunks of 32: ch0 = msg k=0..24 (+k=25 bias row, 1.0 in B), ch1/2 = h bf16.
// Weights pre-scaled: i,f,o rows by -log2(e); g rows by +2*log2(e).
// Block = 4 waves (256 thr) = 16 batch rows; wave cg owns h-units [16cg,16cg+16).
//
// R19 vs R18/R12 (92.6us): activation cleanup (one variable):
//  * direct tanh: (t-1)*rcp(t+1) on the SIGNED exponent (g pre-scaled +2log2e)
//    -> no fabs/copysign (2 v_bfi/cell removed). Safe: overflow needs |x|>44,
//    data gives |gate|~N(0,1), |c|<~4.
//  * activations on f32x4 vectors (v_pk_* pairs, no f32x2 extract movs).

using bf16x8 = __attribute__((ext_vector_type(8))) short;
using f32x4  = __attribute__((ext_vector_type(4))) float;

union U16B { uint4 u; bf16x8 v; };

#define KE  1.4426950408889634f
#define K2E 2.8853900817779268f

__device__ __forceinline__ unsigned short f2bf(float x) {
    unsigned int u = __float_as_uint(x);
    u += 0x7FFFu + ((u >> 16) & 1u);           // RNE
    return (unsigned short)(u >> 16);
}
__device__ __forceinline__ float bf2f(unsigned short h) {
    return __uint_as_float(((unsigned int)h) << 16);
}

// A-fragment layout for 16x16x32: lane holds A[row=lane&15][k=(lane>>4)*8+j], j=0..7.
// wfrag[((ch*16+gt)*64+lane)*8+j]: tile gt covers gunits [16gt,16gt+16).
// ch0: combT[gunit][k] (k<25), k==25 -> bias; ch1/2: Whh[gunit][k].
// All values pre-scaled by s(gate): gate=gunit>>6 (i,f,g,o); s = (gate==2)? +K2E : -KE.
__global__ void prep_kernel(const float* __restrict__ emb,
                            const float* __restrict__ Wih,
                            const float* __restrict__ Whh,
                            const float* __restrict__ bih,
                            const float* __restrict__ bhh,
                            unsigned short* __restrict__ wfrag) {
    const int b = blockIdx.x, tid = threadIdx.x;
    const int ch = b >> 4, gt = b & 15;
    const int lane = tid >> 3, j = tid & 7;
    const int kloc = (lane >> 4) * 8 + j;       // 0..31
    const int gunit = 16 * gt + (lane & 15);    // 0..255
    float v = 0.f;
    if (ch == 0) {
        if (kloc < 25) {
            const float* ep = emb + kloc * 64;
            const float* wp = Wih + gunit * 64;
            float s = 0.f;
            #pragma unroll
            for (int e = 0; e < 64; ++e) s = fmaf(ep[e], wp[e], s);
            v = s;
        } else if (kloc == 25) {
            v = bih[gunit] + bhh[gunit];        // bias row
        }
    } else {
        v = Whh[gunit * 64 + (ch - 1) * 32 + kloc];
    }
    const int gate = gunit >> 6;
    const float s = (gate == 2) ? K2E : -KE;
    wfrag[((ch * 16 + gt) * 64 + lane) * 8 + j] = f2bf(s * v);
}

#define CVTPK(D, A, B_)                                                      \
    asm("v_cvt_pk_bf16_f32 %0, %1, %2" : "=v"(D) : "v"(A), "v"(B_));

// LDS-only barrier: h exchange needs lgkmcnt drained, NOT vmcnt — msg
// prefetch loads stay in flight across the barrier.
#define BARRIER()                                                            \
    asm volatile("s_waitcnt lgkmcnt(0)\n\ts_barrier" ::: "memory");

// Load next msg slice as raw f32 (8 regs) from PTR; consumed 2 steps later.
#define LOADMSG(DST, PTR)                                                    \
    {                                                                        \
        const float* p_ = (PTR) + kq;                                        \
        if (kq < 24) {                                                       \
            _Pragma("unroll") for (int j = 0; j < 8; ++j) DST[j] = p_[j];    \
        } else {                                                             \
            DST[0] = p_[0]; DST[1] = 1.0f;   /* bias row k=25 */             \
            _Pragma("unroll") for (int j = 2; j < 8; ++j) DST[j] = 0.f;      \
        }                                                                    \
    }

#define CONVMSG(MB, MF)                                                      \
    {                                                                        \
        CVTPK(MB.u.x, MF[0], MF[1]) CVTPK(MB.u.y, MF[2], MF[3])              \
        CVTPK(MB.u.z, MF[4], MF[5]) CVTPK(MB.u.w, MF[6], MF[7])              \
    }

// One LSTM step. MF holds step S's msg (f32), refilled with step S+2's.
// Activation math (signs from prescale: i/f/o rows * -log2e, g rows * +2log2e):
//   ti=2^acc_i=e^{-ai}; sig(ai)=1/(1+ti).  tg=2^acc_g=e^{2ag};
//   tanh(ag)=(tg-1)/(tg+1).  i*g = (tg-1)/P, P=(1+ti)(1+tg).
//   f=1/F, F=1+tf.  cn=[c*P+(tg-1)*F]/(P*F).
//   tc=e^{2cn}; h = o*tanh(cn) = (tc-1)/((1+to)(1+tc)).
#define STEP(S, CURB, NXTB, MF)                                              \
    {                                                                        \
        bf16x8 bh0, bh1;                                                     \
        {                                                                    \
            int o0_ = (l16 * 128 + 0 * 64 + lq * 16) ^ swz;                  \
            int o1_ = (l16 * 128 + 1 * 64 + lq * 16) ^ swz;                  \
            bh0 = *(const bf16x8*)((CURB) + o0_);                            \
            bh1 = *(const bf16x8*)((CURB) + o1_);                            \
        }                                                                    \
        U16B mc_;                                                            \
        CONVMSG(mc_, MF)                                                     \
        if ((S) < 62) { LOADMSG(MF, mp) }                                    \
        mp += 25;                                                            \
        f32x4 acc[4];                                                        \
        _Pragma("unroll") for (int i = 0; i < 4; ++i)                        \
            acc[i] = __builtin_amdgcn_mfma_f32_16x16x32_bf16(                \
                w[0][i], mc_.v, z4, 0, 0, 0);                                \
        _Pragma("unroll") for (int i = 0; i < 4; ++i)                        \
            acc[i] = __builtin_amdgcn_mfma_f32_16x16x32_bf16(                \
                w[1][i], bh0, acc[i], 0, 0, 0);                              \
        _Pragma("unroll") for (int i = 0; i < 4; ++i)                        \
            acc[i] = __builtin_amdgcn_mfma_f32_16x16x32_bf16(                \
                w[2][i], bh1, acc[i], 0, 0, 0);                              \
        f32x4 ti, tf_, tg, to_;                                              \
        _Pragma("unroll") for (int q = 0; q < 4; ++q) {                      \
            ti[q]  = __builtin_amdgcn_exp2f(acc[0][q]);                      \
            tf_[q] = __builtin_amdgcn_exp2f(acc[1][q]);                      \
            tg[q]  = __builtin_amdgcn_exp2f(acc[2][q]);                      \
            to_[q] = __builtin_amdgcn_exp2f(acc[3][q]);                      \
        }                                                                    \
        f32x4 F_ = tf_ + 1.f;                                                \
        f32x4 P_ = (ti + 1.f) * (tg + 1.f);                                  \
        f32x4 D_ = P_ * F_;                                                  \
        f32x4 G_ = (tg - 1.f) * F_;                                          \
        f32x4 num_ = c4 * P_ + G_;                                           \
        f32x4 rD_;                                                           \
        _Pragma("unroll") for (int q = 0; q < 4; ++q)                        \
            rD_[q] = __builtin_amdgcn_rcpf(D_[q]);                           \
        f32x4 cn_ = num_ * rD_;                                              \
        c4 = cn_;                                                            \
        f32x4 kc_ = cn_ * K2E;                                               \
        f32x4 tc_;                                                           \
        _Pragma("unroll") for (int q = 0; q < 4; ++q)                        \
            tc_[q] = __builtin_amdgcn_exp2f(kc_[q]);                         \
        f32x4 D2_ = (to_ + 1.f) * (tc_ + 1.f);                               \
        f32x4 rD2_;                                                          \
        _Pragma("unroll") for (int q = 0; q < 4; ++q)                        \
            rD2_[q] = __builtin_amdgcn_rcpf(D2_[q]);                         \
        f32x4 h_ = (tc_ - 1.f) * rD2_;                                       \
        unsigned hw0_, hw1_;                                                 \
        CVTPK(hw0_, h_[0], h_[1]) CVTPK(hw1_, h_[2], h_[3])                  \
        *(uint2*)((NXTB) + offw) = make_uint2(hw0_, hw1_);                   \
        BARRIER()                                                            \
    }

__global__ __launch_bounds__(256, 4) void lstm_mfma(
    const float* __restrict__ msgs,
    const unsigned short* __restrict__ wfrag,
    const float* __restrict__ fcw,
    const float* __restrict__ fcb,
    float* __restrict__ out)
{
    // double-buffered h: buf = h[16 brows][64 units] bf16 = 2KB, x2
    __shared__ __align__(16) char lds[4096];

    const int tid  = threadIdx.x;
    const int lane = tid & 63;
    const int cg   = __builtin_amdgcn_readfirstlane(tid >> 6); // 0..3 (SGPR)
    const int l16  = lane & 15;                 // batch row within tile
    const int lq   = lane >> 4;                 // k-quad / unit-quad
    const int row0 = blockIdx.x * 16;
    const int kq   = lq * 8;                    // k base within chunk

    // weight A-fragments in VGPRs: gate i -> tile 4i+cg, 3 chunks (48 regs)
    bf16x8 w[3][4];
    #pragma unroll
    for (int ch = 0; ch < 3; ++ch)
        #pragma unroll
        for (int i = 0; i < 4; ++i)
            w[ch][i] = *(const bf16x8*)(wfrag + ((ch * 16 + 4 * i + cg) * 64 + lane) * 8);

    // zero h buffer 0 (2KB)
    for (int idx = tid; idx < 512; idx += 256) ((unsigned int*)lds)[idx] = 0u;

    // persistent zero C-operand for the first MFMA of each chain
    const f32x4 z4 = (f32x4){0.f, 0.f, 0.f, 0.f};

    f32x4 c4 = (f32x4){0.f, 0.f, 0.f, 0.f};

    const float* mrow = msgs + (long)(row0 + l16) * 1600;
    const float* mp   = mrow + 50;              // next msg slice to prefetch (s=2)
    const int swz  = (l16 & 7) << 4;
    // this thread writes h[brow=l16][units 16cg+4lq .. +3] -> 8B
    const int offw = (l16 * 128 + cg * 32 + lq * 8) ^ swz;

    float mfA[8], mfB[8];
    LOADMSG(mfA, mrow)
    LOADMSG(mfB, mrow + 25)
    __syncthreads();   // one-time full barrier (zeroed LDS visible)

    char* b0 = (char*)lds;
    char* b1 = b0 + 2048;
    for (int s2 = 0; s2 < 64; s2 += 2) {
        STEP(s2,     b0, b1, mfA)
        STEP(s2 + 1, b1, b0, mfB)
    }

    // final h in b0 as h[brow][unit]. FC epilogue: thread -> (row, class)
    if (tid < 64) {
        const int r = tid >> 2, cls = tid & 3;
        if (cls < 3) {
            float a = fcb[cls];
            const int sw = (r & 7) << 4;
            #pragma unroll
            for (int u = 0; u < 64; ++u) {
                int off = (r * 128 + u * 2) ^ sw;
                float hv = bf2f(*(const unsigned short*)(b0 + off));
                a = fmaf(hv, fcw[cls * 64 + u], a);
            }
            out[(row0 + r) * 3 + cls] = a;
        }
    }
}

extern "C" void kernel_launch(void* const* d_in, const int* in_sizes, int n_in,
                              void* d_out, int out_size, void* d_ws, size_t ws_size,
                              hipStream_t stream) {
    const float* msgs = (const float*)d_in[0];
    const float* emb  = (const float*)d_in[1];
    const float* Wih  = (const float*)d_in[2];
    const float* Whh  = (const float*)d_in[3];
    const float* bih  = (const float*)d_in[4];
    const float* bhh  = (const float*)d_in[5];
    const float* fcw  = (const float*)d_in[6];
    const float* fcb  = (const float*)d_in[7];
    float* out = (float*)d_out;

    // ws: wfrag bf16[3*16*64*8] = 49152 B
    unsigned short* wfrag = (unsigned short*)d_ws;

    prep_kernel<<<48, 512, 0, stream>>>(emb, Wih, Whh, bih, bhh, wfrag);
    lstm_mfma<<<16384 / 16, 256, 0, stream>>>(msgs, wfrag, fcw, fcb, out);
}